// Round 13
// baseline (332.468 us; speedup 1.0000x reference)
//
#include <hip/hip_runtime.h>
#include <cfloat>
#include <cstdint>
#include <climits>

// Problem constants (YOLOv8 640x640 head)
#define NB 64
#define NG 32
#define NC 80
#define NA 8400
#define KTOP 13
#define CHUNK 256
#define NCH 33                 // ceil(NA/CHUNK)
#define NCAND (NCH * KTOP)     // 429 candidates per (b,g)
#define GGRP 16                // g's per LDS group (2 groups of 16)

// lex compare-exchange, descending (key desc, idx asc on ties) — branchless
#define CE(ka, ia, kb, ib)                                            \
    {                                                                 \
        const bool sw = (ka < kb) || (ka == kb && ia > ib);           \
        const unsigned tk = sw ? kb : ka;                             \
        const int      ti = sw ? ib : ia;                             \
        kb = sw ? ka : kb;  ib = sw ? ia : ib;                        \
        ka = tk;            ia = ti;                                  \
    }

// Wave64 max-reduce on the VALU pipe via DPP (no LDS/ds_bpermute traffic).
// Signed i32 max: positive-float bit patterns are monotone positive ints,
// -FLT_MAX is negative; bound_ctrl=true injects 0 for invalid lanes, which
// never wins as long as at least one lane holds a positive key (always true
// where this is used). HW-verified R1/R5/R6/R7/R11 (absmax 0.0).
__device__ __forceinline__ int wave_max_pos(int m) {
    m = max(m, __builtin_amdgcn_update_dpp(0, m, 0x111, 0xF, 0xF, true)); // row_shr:1
    m = max(m, __builtin_amdgcn_update_dpp(0, m, 0x112, 0xF, 0xF, true)); // row_shr:2
    m = max(m, __builtin_amdgcn_update_dpp(0, m, 0x114, 0xF, 0xF, true)); // row_shr:4
    m = max(m, __builtin_amdgcn_update_dpp(0, m, 0x118, 0xF, 0xF, true)); // row_shr:8
    m = max(m, __builtin_amdgcn_update_dpp(0, m, 0x142, 0xF, 0xF, true)); // row_bcast:15
    m = max(m, __builtin_amdgcn_update_dpp(0, m, 0x143, 0xF, 0xF, true)); // row_bcast:31
    return __builtin_amdgcn_readlane(m, 63);
}

// ---------------------------------------------------------------------------
// Fused A+B, v6: identical math to v5; __launch_bounds__(256, 2) relaxes the
// compiler's 8-waves/SIMD occupancy target (VGPR cap 64 -> ~256) so cls[80]
// and the 4-wide tournament state actually LIVE in registers. At VGPR=56 the
// compiler was chunking the class loop and re-reading pass 2 through L2 —
// the dominant stall (measured occupancy is ~2.75 waves/SIMD anyway, so the
// relaxed target costs nothing).
// ---------------------------------------------------------------------------
__global__ __launch_bounds__(256, 2) void fusedAB(
    const float* __restrict__ preds,          // (B, 84, A)
    const float* __restrict__ gt_bboxes,      // (B, G, 4)
    const int*   __restrict__ gt_classes,     // (B, G)
    const float* __restrict__ anchor_points,  // (A, 2)
    float2*      __restrict__ aux_ws,         // (B*A) (mx, rdenom)
    unsigned*    __restrict__ inside32,       // (B*A)
    int*         __restrict__ bestg,          // (B*A)
    float*       __restrict__ candv,          // (B*G, NCH, 13)
    int*         __restrict__ candi,          // (B*G, NCH, 13)
    float*       __restrict__ out_sum)        // scalar, zeroed here
{
    __shared__ float sx1[NG], sy1[NG], sx2[NG], sy2[NG], sarea[NG];
    __shared__ int   scls[NG];
    __shared__ __align__(16) float salign[GGRP][CHUNK];  // 16 KB
    __shared__ __align__(16) float sdist[4][CHUNK];      // 4 KB: l,t,r,b planes

    const int tid   = threadIdx.x;
    const int chunk = blockIdx.x;
    const int b     = blockIdx.y;
    const int abase = chunk * CHUNK;
    const int a0    = abase + tid;            // 1 anchor per thread
    const bool live = (a0 < NA);

    if (tid < NG) {
        const float* gb = gt_bboxes + ((size_t)b * NG + tid) * 4;
        const float x1 = gb[0], y1 = gb[1], x2 = gb[2], y2 = gb[3];
        sx1[tid] = x1; sy1[tid] = y1; sx2[tid] = x2; sy2[tid] = y2;
        sarea[tid] = (x2 - x1) * (y2 - y1);
        scls[tid]  = gt_classes[b * NG + tid];
    }
    if (b == 0 && chunk == 0 && tid == 0) out_sum[0] = 0.0f;

    // ---- stage dist planes cooperatively: 1 float4 per thread ----
    {
        const int p = tid >> 6, k = tid & 63;   // plane 0..3, float4 idx 0..63
        float4 v = make_float4(0.0f, 0.0f, 0.0f, 0.0f);
        if (abase + 4 * k < NA)   // NA%4==0, abase%256==0 -> clean live/dead split
            v = *(const float4*)(preds + ((size_t)b * (4 + NC) + p) * NA + abase + 4 * k);
        *(float4*)&sdist[p][4 * k] = v;
    }
    __syncthreads();   // also covers sx1../scls writes above

    // ---- per-thread decode (dist from LDS, bit-identical values) ----
    float ax = 0, ay = 0, x1 = 0, y1 = 0, x2 = 0, y2 = 0, area = 0;
    if (live) {
        const float2 ap = *(const float2*)(anchor_points + (size_t)a0 * 2);
        ax = ap.x; ay = ap.y;
        const float l  = sdist[0][tid];
        const float t  = sdist[1][tid];
        const float r  = sdist[2][tid];
        const float bo = sdist[3][tid];
        x1 = ax - l; y1 = ay - t; x2 = ax + r; y2 = ay + bo;
        area = (x2 - x1) * (y2 - y1);
    }

    const float* cb = preds + ((size_t)b * (4 + NC) + 4) * NA + a0;  // class base

    // ---- all 80 class logits -> registers (static indices only) ----
    float cls[NC];
    if (live) {
#pragma unroll
        for (int c = 0; c < NC; ++c) cls[c] = cb[(size_t)c * NA];
    } else {
#pragma unroll
        for (int c = 0; c < NC; ++c) cls[c] = 0.0f;
    }

    // ---- softmax pass 1: max (4-chain tree; fmax associative -> exact) ----
    float m0 = cls[0], m1 = cls[1], m2 = cls[2], m3 = cls[3];
#pragma unroll
    for (int c = 4; c < NC; c += 4) {
        m0 = fmaxf(m0, cls[c]);
        m1 = fmaxf(m1, cls[c + 1]);
        m2 = fmaxf(m2, cls[c + 2]);
        m3 = fmaxf(m3, cls[c + 3]);
    }
    const float mx = fmaxf(fmaxf(m0, m1), fmaxf(m2, m3));

    // ---- softmax pass 2: sum of exp, EXACT ascending class order ----
    float d = 0.0f;
#pragma unroll
    for (int c = 0; c < NC; ++c) d += __expf(cls[c] - mx);
    const float rd = 1.0f / d;     // dead lanes: value irrelevant (never stored/used)

    unsigned ins = 0u;
    int   bg = 0;
    float bi = -1.0f;       // strict > keeps first max (jnp.argmax)

    const int lane = tid & 63;
    const int wid  = tid >> 6;

    // ---- 2 groups of 16 g's: compute -> LDS -> per-wave topk ----
    for (int grp = 0; grp < 2; ++grp) {
        if (live) {
            // prefetch this group's 16 class-prob gathers (batched issue)
            float cvl[GGRP];
#pragma unroll
            for (int gg = 0; gg < GGRP; ++gg)
                cvl[gg] = cb[(size_t)scls[grp * GGRP + gg] * NA];
#pragma unroll
            for (int gg = 0; gg < GGRP; ++gg) {
                const int g = grp * GGRP + gg;
                const float bx1 = sx1[g], by1 = sy1[g], bx2 = sx2[g], by2 = sy2[g];
                const float sag = sarea[g];
                const float ltx = fmaxf(x1, bx1), lty = fmaxf(y1, by1);
                const float rbx = fminf(x2, bx2), rby = fminf(y2, by2);
                const float w = fmaxf(rbx - ltx, 0.0f), h = fmaxf(rby - lty, 0.0f);
                const float inter = w * h;
                const float iou = inter / (area + sag - inter + 1e-7f);
                if (iou > bi) { bi = iou; bg = g; }
                const float cv = __expf(cvl[gg] - mx) * rd;
                const float al = sqrtf(fmaxf(iou, 1e-12f)) * sqrtf(fmaxf(cv, 1e-12f));
                const float dmin = fminf(fminf(ax - bx1, ay - by1), fminf(bx2 - ax, by2 - ay));
                if (dmin > 1e-9f) ins |= (1u << g);
                salign[gg][tid] = al;     // al > 0 always
            }
        } else {
            // dead anchors (last chunk): sentinel key 0 (< any positive float)
#pragma unroll
            for (int gg = 0; gg < GGRP; ++gg) salign[gg][tid] = 0.0f;
        }
        __syncthreads();

        // topk: wave wid handles gg = wid*4 .. wid*4+3 — ALL FOUR concurrently
        {
            const int gg0 = wid * 4;
            const float4 qA = *(const float4*)&salign[gg0 + 0][lane * 4];
            const float4 qB = *(const float4*)&salign[gg0 + 1][lane * 4];
            const float4 qC = *(const float4*)&salign[gg0 + 2][lane * 4];
            const float4 qD = *(const float4*)&salign[gg0 + 3][lane * 4];
            unsigned A0 = __float_as_uint(qA.x), A1 = __float_as_uint(qA.y);
            unsigned A2 = __float_as_uint(qA.z), A3 = __float_as_uint(qA.w);
            unsigned B0 = __float_as_uint(qB.x), B1 = __float_as_uint(qB.y);
            unsigned B2 = __float_as_uint(qB.z), B3 = __float_as_uint(qB.w);
            unsigned C0 = __float_as_uint(qC.x), C1 = __float_as_uint(qC.y);
            unsigned C2 = __float_as_uint(qC.z), C3 = __float_as_uint(qC.w);
            unsigned D0 = __float_as_uint(qD.x), D1 = __float_as_uint(qD.y);
            unsigned D2 = __float_as_uint(qD.z), D3 = __float_as_uint(qD.w);
            // lane takes 4 CONSECUTIVE values -> lane order == index order
            int IA0 = abase + lane * 4, IA1 = IA0 + 1, IA2 = IA0 + 2, IA3 = IA0 + 3;
            int IB0 = IA0, IB1 = IA1, IB2 = IA2, IB3 = IA3;
            int IC0 = IA0, IC1 = IA1, IC2 = IA2, IC3 = IA3;
            int ID0 = IA0, ID1 = IA1, ID2 = IA2, ID3 = IA3;

            // 5-CE lex sort desc (stable): (0,2)(1,3)(0,1)(2,3)(1,2), all sets
            CE(A0, IA0, A2, IA2); CE(A1, IA1, A3, IA3);
            CE(A0, IA0, A1, IA1); CE(A2, IA2, A3, IA3);
            CE(A1, IA1, A2, IA2);
            CE(B0, IB0, B2, IB2); CE(B1, IB1, B3, IB3);
            CE(B0, IB0, B1, IB1); CE(B2, IB2, B3, IB3);
            CE(B1, IB1, B2, IB2);
            CE(C0, IC0, C2, IC2); CE(C1, IC1, C3, IC3);
            CE(C0, IC0, C1, IC1); CE(C2, IC2, C3, IC3);
            CE(C1, IC1, C2, IC2);
            CE(D0, ID0, D2, ID2); CE(D1, ID1, D3, ID3);
            CE(D0, ID0, D1, ID1); CE(D2, ID2, D3, ID3);
            CE(D1, ID1, D2, ID2);

            unsigned rvA = 0u, rvB = 0u, rvC = 0u, rvD = 0u;
            int      riA = 0x7FFFFFFF, riB = 0x7FFFFFFF, riC = 0x7FFFFFFF, riD = 0x7FFFFFFF;
#pragma unroll
            for (int r = 0; r < KTOP; ++r) {
                // four independent DPP reduce chains -> interleaved issue
                const unsigned mA = (unsigned)wave_max_pos((int)A0);
                const unsigned mB = (unsigned)wave_max_pos((int)B0);
                const unsigned mC = (unsigned)wave_max_pos((int)C0);
                const unsigned mD = (unsigned)wave_max_pos((int)D0);
                const unsigned long long blA = __ballot(A0 == mA);
                const unsigned long long blB = __ballot(B0 == mB);
                const unsigned long long blC = __ballot(C0 == mC);
                const unsigned long long blD = __ballot(D0 == mD);
                const int wA = __ffsll(blA) - 1;   // first lane = smallest idx (exact)
                const int wB = __ffsll(blB) - 1;
                const int wC = __ffsll(blC) - 1;
                const int wD = __ffsll(blD) - 1;
                const int xA = __builtin_amdgcn_readlane(IA0, wA);
                const int xB = __builtin_amdgcn_readlane(IB0, wB);
                const int xC = __builtin_amdgcn_readlane(IC0, wC);
                const int xD = __builtin_amdgcn_readlane(ID0, wD);
                if (lane == wA) { A0 = A1; IA0 = IA1; A1 = A2; IA1 = IA2; A2 = A3; IA2 = IA3; A3 = 0u; }
                if (lane == wB) { B0 = B1; IB0 = IB1; B1 = B2; IB1 = IB2; B2 = B3; IB2 = IB3; B3 = 0u; }
                if (lane == wC) { C0 = C1; IC0 = IC1; C1 = C2; IC1 = IC2; C2 = C3; IC2 = IC3; C3 = 0u; }
                if (lane == wD) { D0 = D1; ID0 = ID1; D1 = D2; ID1 = ID2; D2 = D3; ID2 = ID3; D3 = 0u; }
                if (lane == r) {
                    rvA = mA; riA = xA; rvB = mB; riB = xB;
                    rvC = mC; riC = xC; rvD = mD; riD = xD;
                }
            }
            if (lane < KTOP) {
                const int gbase = b * NG + grp * GGRP + gg0;
                const size_t b0 = ((size_t)(gbase + 0) * NCH + chunk) * KTOP + lane;
                const size_t b1 = ((size_t)(gbase + 1) * NCH + chunk) * KTOP + lane;
                const size_t b2 = ((size_t)(gbase + 2) * NCH + chunk) * KTOP + lane;
                const size_t b3 = ((size_t)(gbase + 3) * NCH + chunk) * KTOP + lane;
                candv[b0] = __uint_as_float(rvA);  candi[b0] = riA;
                candv[b1] = __uint_as_float(rvB);  candi[b1] = riB;
                candv[b2] = __uint_as_float(rvC);  candi[b2] = riC;
                candv[b3] = __uint_as_float(rvD);  candi[b3] = riD;
            }
        }
        __syncthreads();
    }

    if (live) {
        const int i = b * NA + a0;
        aux_ws[i] = make_float2(mx, rd);
        inside32[i] = ins;
        bestg[i]    = bg;
    }
}

// ---------------------------------------------------------------------------
// Merge: one wave per (b,g): merge NCH*13=429 candidates -> final top-13.
// (Unchanged — HW-verified, DPP lex-max extraction.)
// ---------------------------------------------------------------------------
__global__ __launch_bounds__(256) void mergeTopK(
    const float* __restrict__ candv,
    const int*   __restrict__ candi,
    int*         __restrict__ topk13)   // (B*G, 13)
{
    const int tid  = threadIdx.x;
    const int lane = tid & 63;
    const int row  = blockIdx.x * 4 + (tid >> 6);   // b*NG + g
    const size_t base = (size_t)row * NCAND;

    float v0 = -FLT_MAX, v1 = -FLT_MAX, v2 = -FLT_MAX, v3 = -FLT_MAX,
          v4 = -FLT_MAX, v5 = -FLT_MAX, v6 = -FLT_MAX;
    int   d0 = 0x7FFFFFFF, d1 = 0x7FFFFFFF, d2 = 0x7FFFFFFF, d3 = 0x7FFFFFFF,
          d4 = 0x7FFFFFFF, d5 = 0x7FFFFFFF, d6 = 0x7FFFFFFF;

    // lane sees <=7 candidates; lex rank-insert (val desc, idx asc), all static
#pragma unroll
    for (int k = 0; k < 7; ++k) {
        const int j0 = lane + 64 * k;
        if (j0 < NCAND) {
            const float x  = candv[base + j0];
            const int   xi = candi[base + j0];
            // rank = count of current entries lex-above (x,xi)
            int r = 0;
            r += (v0 > x) || (v0 == x && d0 < xi);
            r += (v1 > x) || (v1 == x && d1 < xi);
            r += (v2 > x) || (v2 == x && d2 < xi);
            r += (v3 > x) || (v3 == x && d3 < xi);
            r += (v4 > x) || (v4 == x && d4 < xi);
            r += (v5 > x) || (v5 == x && d5 < xi);
            r += (v6 > x) || (v6 == x && d6 < xi);
            // new[j] = j<r ? old[j] : (j==r ? x : old[j-1]); descending order
            v6 = (6 < r) ? v6 : ((6 == r) ? x : v5);  d6 = (6 < r) ? d6 : ((6 == r) ? xi : d5);
            v5 = (5 < r) ? v5 : ((5 == r) ? x : v4);  d5 = (5 < r) ? d5 : ((5 == r) ? xi : d4);
            v4 = (4 < r) ? v4 : ((4 == r) ? x : v3);  d4 = (4 < r) ? d4 : ((4 == r) ? xi : d3);
            v3 = (3 < r) ? v3 : ((3 == r) ? x : v2);  d3 = (3 < r) ? d3 : ((3 == r) ? xi : d2);
            v2 = (2 < r) ? v2 : ((2 == r) ? x : v1);  d2 = (2 < r) ? d2 : ((2 == r) ? xi : d1);
            v1 = (1 < r) ? v1 : ((1 == r) ? x : v0);  d1 = (1 < r) ? d1 : ((1 == r) ? xi : d0);
            v0 = (0 == r) ? x  : v0;                  d0 = (0 == r) ? xi : d0;
        }
    }

    int ri = 0x7FFFFFFF;
#pragma unroll
    for (int rnd = 0; rnd < KTOP; ++rnd) {
        const int hk = __float_as_int(v0);          // head key (signed-monotone)
        const int mk = wave_max_pos(hk);            // wave max value
        // min idx among lanes whose head == mk (idx<=8399 -> key2 >> 0; losers -1)
        const int key2 = (hk == mk) ? (INT_MAX - d0) : -1;
        const int mk2  = wave_max_pos(key2);
        const int midx = INT_MAX - mk2;
        if (hk == mk && d0 == midx) {               // unique winner pops
            v0 = v1; d0 = d1; v1 = v2; d1 = d2; v2 = v3; d2 = d3;
            v3 = v4; d3 = d4; v4 = v5; d4 = d5; v5 = v6; d5 = d6;
            v6 = -FLT_MAX; d6 = 0x7FFFFFFF;
        }
        if (lane == rnd) ri = midx;
    }
    if (lane < KTOP) topk13[(size_t)row * KTOP + lane] = ri;
}

// ---------------------------------------------------------------------------
// Phase C: grid (33, B). Block scatters the batch's 416 winner ids into a
// 256-word LDS bitmask; each anchor thread reads one word. The decoded box
// is recomputed from the dist planes (bit-identical expressions to fusedAB)
// instead of a pb_ws round-trip. out: tb | tc | ts | fg | fg_sum
// ---------------------------------------------------------------------------
__global__ __launch_bounds__(256) void phaseC(
    const float*    __restrict__ gt_bboxes,
    const int*      __restrict__ gt_classes,
    const float*    __restrict__ preds,
    const float*    __restrict__ anchor_points,
    const float2*   __restrict__ aux_ws,
    const int*      __restrict__ topk13,    // (B*G, 13)
    const unsigned* __restrict__ inside32,
    const int*      __restrict__ bestg,
    float*          __restrict__ out)
{
    __shared__ unsigned smask[CHUNK];
    __shared__ float ssum[4];

    const int tid   = threadIdx.x;
    const int b     = blockIdx.y;
    const int abase = blockIdx.x * CHUNK;
    const int a     = abase + tid;

    smask[tid] = 0u;
    __syncthreads();
    for (int j = tid; j < NG * KTOP; j += 256) {
        const int idx = topk13[(size_t)b * NG * KTOP + j];
        const int rel = idx - abase;
        if (rel >= 0 && rel < CHUNK)
            atomicOr(&smask[rel], 1u << (j / KTOP));
    }
    __syncthreads();

    bool fg = false;
    if (a < NA) {
        const int i = b * NA + a;
        unsigned m = smask[tid] & inside32[i];
        const int cnt = __popc(m);

        int tgt;
        if (cnt > 1)       { tgt = bestg[i];     fg = true;  }
        else if (cnt == 1) { tgt = __ffs(m) - 1; fg = true;  }
        else               { tgt = 0;            fg = false; }

        const float f = fg ? 1.0f : 0.0f;
        const float4 gbv = *(const float4*)(gt_bboxes + ((size_t)b * NG + tgt) * 4);
        const float gx1 = gbv.x, gy1 = gbv.y, gx2 = gbv.z, gy2 = gbv.w;
        *(float4*)(out + (size_t)i * 4) = make_float4(gx1 * f, gy1 * f, gx2 * f, gy2 * f);

        const size_t BA = (size_t)NB * NA;
        out[BA * 4 + i] = fg ? (float)gt_classes[b * NG + tgt] : 0.0f;

        float ts = 0.0f;
        if (fg) {
            // recompute box + align(a, tgt) with the same expressions as fusedAB
            const float2 ap = *(const float2*)(anchor_points + (size_t)a * 2);
            const float* db = preds + (size_t)b * (4 + NC) * NA + a;
            const float l  = db[0];
            const float t  = db[(size_t)NA];
            const float r  = db[(size_t)2 * NA];
            const float bo = db[(size_t)3 * NA];
            const float x1 = ap.x - l, y1 = ap.y - t, x2 = ap.x + r, y2 = ap.y + bo;
            const float2 ax = aux_ws[i];
            const float areaA = (x2 - x1) * (y2 - y1);
            const float sag   = (gx2 - gx1) * (gy2 - gy1);
            const float ltx = fmaxf(x1, gx1), lty = fmaxf(y1, gy1);
            const float rbx = fminf(x2, gx2), rby = fminf(y2, gy2);
            const float w = fmaxf(rbx - ltx, 0.0f), h = fmaxf(rby - lty, 0.0f);
            const float inter = w * h;
            const float iou = inter / (areaA + sag - inter + 1e-7f);
            const int cls = gt_classes[b * NG + tgt];
            const float cv = __expf(db[(size_t)(4 + cls) * NA] - ax.x) * ax.y;
            ts = sqrtf(fmaxf(iou, 1e-12f)) * sqrtf(fmaxf(cv, 1e-12f));
        }
        out[BA * 5 + i] = ts;
        out[BA * 6 + i] = f;
    }

    // fg.sum(): ballot per wave -> LDS -> one atomic per block (exact fp32 ints)
    const unsigned long long ball = __ballot(fg);
    if ((tid & 63) == 0) ssum[tid >> 6] = (float)__popcll(ball);
    __syncthreads();
    if (tid == 0) {
        const float s = ssum[0] + ssum[1] + ssum[2] + ssum[3];
        if (s != 0.0f) atomicAdd(&out[(size_t)NB * NA * 7], s);
    }
}

// ---------------------------------------------------------------------------
extern "C" void kernel_launch(void* const* d_in, const int* in_sizes, int n_in,
                              void* d_out, int out_size, void* d_ws, size_t ws_size,
                              hipStream_t stream) {
    const float* preds         = (const float*)d_in[0];
    const float* gt_bboxes     = (const float*)d_in[1];
    const int*   gt_classes    = (const int*)  d_in[2];
    const float* anchor_points = (const float*)d_in[3];
    // d_in[4] stride_tensor: unused by the reference math

    float* out = (float*)d_out;
    const size_t BA = (size_t)NB * NA;

    // workspace carve-up (16B-aligned first): aux | inside | bestg | candv | candi | topk13
    char* ws = (char*)d_ws;
    size_t off = 0;
    float2*   aux_ws   = (float2*)(ws + off);   off += BA * sizeof(float2);
    unsigned* inside32 = (unsigned*)(ws + off); off += BA * sizeof(unsigned);
    int*      bestg    = (int*)(ws + off);      off += BA * sizeof(int);
    float*    candv    = (float*)(ws + off);    off += (size_t)NB * NG * NCAND * sizeof(float);
    int*      candi    = (int*)(ws + off);      off += (size_t)NB * NG * NCAND * sizeof(int);
    int*      topk13   = (int*)(ws + off);

    fusedAB<<<dim3(NCH, NB), 256, 0, stream>>>(preds, gt_bboxes, gt_classes, anchor_points,
                                               aux_ws, inside32, bestg,
                                               candv, candi, out + BA * 7);

    mergeTopK<<<NB * NG / 4, 256, 0, stream>>>(candv, candi, topk13);

    phaseC<<<dim3(NCH, NB), 256, 0, stream>>>(gt_bboxes, gt_classes, preds, anchor_points,
                                              aux_ws, topk13,
                                              inside32, bestg, out);
}

// Round 14
// 331.951 us; speedup vs baseline: 1.0016x; 1.0016x over previous
//
#include <hip/hip_runtime.h>
#include <cfloat>
#include <cstdint>
#include <climits>

// Problem constants (YOLOv8 640x640 head)
#define NB 64
#define NG 32
#define NC 80
#define NA 8400
#define KTOP 13
#define CHUNK 256
#define NCH 33                 // ceil(NA/CHUNK)
#define NCAND (NCH * KTOP)     // 429 candidates per (b,g)
#define GGRP 16                // g's per LDS group (2 groups of 16)

// lex compare-exchange, descending (key desc, idx asc on ties) — branchless
#define CE(ka, ia, kb, ib)                                            \
    {                                                                 \
        const bool sw = (ka < kb) || (ka == kb && ia > ib);           \
        const unsigned tk = sw ? kb : ka;                             \
        const int      ti = sw ? ib : ia;                             \
        kb = sw ? ka : kb;  ib = sw ? ia : ib;                        \
        ka = tk;            ia = ti;                                  \
    }

// Wave64 max-reduce on the VALU pipe via DPP (no LDS/ds_bpermute traffic).
// Signed i32 max: positive-float bit patterns are monotone positive ints,
// -FLT_MAX is negative; bound_ctrl=true injects 0 for invalid lanes, which
// never wins as long as at least one lane holds a positive key (always true
// where this is used). HW-verified R1/R5/R6/R7/R11/R13 (absmax 0.0).
__device__ __forceinline__ int wave_max_pos(int m) {
    m = max(m, __builtin_amdgcn_update_dpp(0, m, 0x111, 0xF, 0xF, true)); // row_shr:1
    m = max(m, __builtin_amdgcn_update_dpp(0, m, 0x112, 0xF, 0xF, true)); // row_shr:2
    m = max(m, __builtin_amdgcn_update_dpp(0, m, 0x114, 0xF, 0xF, true)); // row_shr:4
    m = max(m, __builtin_amdgcn_update_dpp(0, m, 0x118, 0xF, 0xF, true)); // row_shr:8
    m = max(m, __builtin_amdgcn_update_dpp(0, m, 0x142, 0xF, 0xF, true)); // row_bcast:15
    m = max(m, __builtin_amdgcn_update_dpp(0, m, 0x143, 0xF, 0xF, true)); // row_bcast:31
    return __builtin_amdgcn_readlane(m, 63);
}

// ---------------------------------------------------------------------------
// Fused A+B, v7: v6 + REGISTER PINNING of cls[80].
// R13 showed the compiler keeps VGPR=56 even with launch_bounds(256,2): it
// legally re-loads cls[] in pass 2 instead of keeping 80 values live, which
// caps memory-level parallelism (~8-16 loads in flight -> 1.2 TB/s pinned
// across ALL variants). The opaque asm "+v" makes the register the value's
// source: the 80 loads become simultaneously issuable (5x MLP) and pass-2's
// 80 L2 re-reads vanish. Bit-exact no-op on values.
// ---------------------------------------------------------------------------
__global__ __launch_bounds__(256, 2) void fusedAB(
    const float* __restrict__ preds,          // (B, 84, A)
    const float* __restrict__ gt_bboxes,      // (B, G, 4)
    const int*   __restrict__ gt_classes,     // (B, G)
    const float* __restrict__ anchor_points,  // (A, 2)
    float2*      __restrict__ aux_ws,         // (B*A) (mx, rdenom)
    unsigned*    __restrict__ inside32,       // (B*A)
    int*         __restrict__ bestg,          // (B*A)
    float*       __restrict__ candv,          // (B*G, NCH, 13)
    int*         __restrict__ candi,          // (B*G, NCH, 13)
    float*       __restrict__ out_sum)        // scalar, zeroed here
{
    __shared__ float sx1[NG], sy1[NG], sx2[NG], sy2[NG], sarea[NG];
    __shared__ int   scls[NG];
    __shared__ __align__(16) float salign[GGRP][CHUNK];  // 16 KB
    __shared__ __align__(16) float sdist[4][CHUNK];      // 4 KB: l,t,r,b planes

    const int tid   = threadIdx.x;
    const int chunk = blockIdx.x;
    const int b     = blockIdx.y;
    const int abase = chunk * CHUNK;
    const int a0    = abase + tid;            // 1 anchor per thread
    const bool live = (a0 < NA);

    if (tid < NG) {
        const float* gb = gt_bboxes + ((size_t)b * NG + tid) * 4;
        const float x1 = gb[0], y1 = gb[1], x2 = gb[2], y2 = gb[3];
        sx1[tid] = x1; sy1[tid] = y1; sx2[tid] = x2; sy2[tid] = y2;
        sarea[tid] = (x2 - x1) * (y2 - y1);
        scls[tid]  = gt_classes[b * NG + tid];
    }
    if (b == 0 && chunk == 0 && tid == 0) out_sum[0] = 0.0f;

    // ---- stage dist planes cooperatively: 1 float4 per thread ----
    {
        const int p = tid >> 6, k = tid & 63;   // plane 0..3, float4 idx 0..63
        float4 v = make_float4(0.0f, 0.0f, 0.0f, 0.0f);
        if (abase + 4 * k < NA)   // NA%4==0, abase%256==0 -> clean live/dead split
            v = *(const float4*)(preds + ((size_t)b * (4 + NC) + p) * NA + abase + 4 * k);
        *(float4*)&sdist[p][4 * k] = v;
    }
    __syncthreads();   // also covers sx1../scls writes above

    // ---- per-thread decode (dist from LDS, bit-identical values) ----
    float ax = 0, ay = 0, x1 = 0, y1 = 0, x2 = 0, y2 = 0, area = 0;
    if (live) {
        const float2 ap = *(const float2*)(anchor_points + (size_t)a0 * 2);
        ax = ap.x; ay = ap.y;
        const float l  = sdist[0][tid];
        const float t  = sdist[1][tid];
        const float r  = sdist[2][tid];
        const float bo = sdist[3][tid];
        x1 = ax - l; y1 = ay - t; x2 = ax + r; y2 = ay + bo;
        area = (x2 - x1) * (y2 - y1);
    }

    const float* cb = preds + ((size_t)b * (4 + NC) + 4) * NA + a0;  // class base

    // ---- all 80 class logits -> registers (static indices only) ----
    float cls[NC];
    if (live) {
#pragma unroll
        for (int c = 0; c < NC; ++c) cls[c] = cb[(size_t)c * NA];
    } else {
#pragma unroll
        for (int c = 0; c < NC; ++c) cls[c] = 0.0f;
    }
    // PIN: value now sourced from the register — compiler cannot re-load it.
    // Forces all 80 loads in flight (MLP) and kills pass-2 L2 re-reads.
#pragma unroll
    for (int c = 0; c < NC; ++c) asm volatile("" : "+v"(cls[c]));

    // ---- softmax pass 1: max (4-chain tree; fmax associative -> exact) ----
    float m0 = cls[0], m1 = cls[1], m2 = cls[2], m3 = cls[3];
#pragma unroll
    for (int c = 4; c < NC; c += 4) {
        m0 = fmaxf(m0, cls[c]);
        m1 = fmaxf(m1, cls[c + 1]);
        m2 = fmaxf(m2, cls[c + 2]);
        m3 = fmaxf(m3, cls[c + 3]);
    }
    const float mx = fmaxf(fmaxf(m0, m1), fmaxf(m2, m3));

    // ---- softmax pass 2: sum of exp, EXACT ascending class order ----
    float d = 0.0f;
#pragma unroll
    for (int c = 0; c < NC; ++c) d += __expf(cls[c] - mx);
    const float rd = 1.0f / d;     // dead lanes: value irrelevant (never stored/used)

    unsigned ins = 0u;
    int   bg = 0;
    float bi = -1.0f;       // strict > keeps first max (jnp.argmax)

    const int lane = tid & 63;
    const int wid  = tid >> 6;

    // ---- 2 groups of 16 g's: compute -> LDS -> per-wave topk ----
    for (int grp = 0; grp < 2; ++grp) {
        if (live) {
            // prefetch this group's 16 class-prob gathers (batched issue)
            float cvl[GGRP];
#pragma unroll
            for (int gg = 0; gg < GGRP; ++gg)
                cvl[gg] = cb[(size_t)scls[grp * GGRP + gg] * NA];
#pragma unroll
            for (int gg = 0; gg < GGRP; ++gg) {
                const int g = grp * GGRP + gg;
                const float bx1 = sx1[g], by1 = sy1[g], bx2 = sx2[g], by2 = sy2[g];
                const float sag = sarea[g];
                const float ltx = fmaxf(x1, bx1), lty = fmaxf(y1, by1);
                const float rbx = fminf(x2, bx2), rby = fminf(y2, by2);
                const float w = fmaxf(rbx - ltx, 0.0f), h = fmaxf(rby - lty, 0.0f);
                const float inter = w * h;
                const float iou = inter / (area + sag - inter + 1e-7f);
                if (iou > bi) { bi = iou; bg = g; }
                const float cv = __expf(cvl[gg] - mx) * rd;
                const float al = sqrtf(fmaxf(iou, 1e-12f)) * sqrtf(fmaxf(cv, 1e-12f));
                const float dmin = fminf(fminf(ax - bx1, ay - by1), fminf(bx2 - ax, by2 - ay));
                if (dmin > 1e-9f) ins |= (1u << g);
                salign[gg][tid] = al;     // al > 0 always
            }
        } else {
            // dead anchors (last chunk): sentinel key 0 (< any positive float)
#pragma unroll
            for (int gg = 0; gg < GGRP; ++gg) salign[gg][tid] = 0.0f;
        }
        __syncthreads();

        // topk: wave wid handles gg = wid*4 .. wid*4+3 — ALL FOUR concurrently
        {
            const int gg0 = wid * 4;
            const float4 qA = *(const float4*)&salign[gg0 + 0][lane * 4];
            const float4 qB = *(const float4*)&salign[gg0 + 1][lane * 4];
            const float4 qC = *(const float4*)&salign[gg0 + 2][lane * 4];
            const float4 qD = *(const float4*)&salign[gg0 + 3][lane * 4];
            unsigned A0 = __float_as_uint(qA.x), A1 = __float_as_uint(qA.y);
            unsigned A2 = __float_as_uint(qA.z), A3 = __float_as_uint(qA.w);
            unsigned B0 = __float_as_uint(qB.x), B1 = __float_as_uint(qB.y);
            unsigned B2 = __float_as_uint(qB.z), B3 = __float_as_uint(qB.w);
            unsigned C0 = __float_as_uint(qC.x), C1 = __float_as_uint(qC.y);
            unsigned C2 = __float_as_uint(qC.z), C3 = __float_as_uint(qC.w);
            unsigned D0 = __float_as_uint(qD.x), D1 = __float_as_uint(qD.y);
            unsigned D2 = __float_as_uint(qD.z), D3 = __float_as_uint(qD.w);
            // lane takes 4 CONSECUTIVE values -> lane order == index order
            int IA0 = abase + lane * 4, IA1 = IA0 + 1, IA2 = IA0 + 2, IA3 = IA0 + 3;
            int IB0 = IA0, IB1 = IA1, IB2 = IA2, IB3 = IA3;
            int IC0 = IA0, IC1 = IA1, IC2 = IA2, IC3 = IA3;
            int ID0 = IA0, ID1 = IA1, ID2 = IA2, ID3 = IA3;

            // 5-CE lex sort desc (stable): (0,2)(1,3)(0,1)(2,3)(1,2), all sets
            CE(A0, IA0, A2, IA2); CE(A1, IA1, A3, IA3);
            CE(A0, IA0, A1, IA1); CE(A2, IA2, A3, IA3);
            CE(A1, IA1, A2, IA2);
            CE(B0, IB0, B2, IB2); CE(B1, IB1, B3, IB3);
            CE(B0, IB0, B1, IB1); CE(B2, IB2, B3, IB3);
            CE(B1, IB1, B2, IB2);
            CE(C0, IC0, C2, IC2); CE(C1, IC1, C3, IC3);
            CE(C0, IC0, C1, IC1); CE(C2, IC2, C3, IC3);
            CE(C1, IC1, C2, IC2);
            CE(D0, ID0, D2, ID2); CE(D1, ID1, D3, ID3);
            CE(D0, ID0, D1, ID1); CE(D2, ID2, D3, ID3);
            CE(D1, ID1, D2, ID2);

            unsigned rvA = 0u, rvB = 0u, rvC = 0u, rvD = 0u;
            int      riA = 0x7FFFFFFF, riB = 0x7FFFFFFF, riC = 0x7FFFFFFF, riD = 0x7FFFFFFF;
#pragma unroll
            for (int r = 0; r < KTOP; ++r) {
                // four independent DPP reduce chains -> interleaved issue
                const unsigned mA = (unsigned)wave_max_pos((int)A0);
                const unsigned mB = (unsigned)wave_max_pos((int)B0);
                const unsigned mC = (unsigned)wave_max_pos((int)C0);
                const unsigned mD = (unsigned)wave_max_pos((int)D0);
                const unsigned long long blA = __ballot(A0 == mA);
                const unsigned long long blB = __ballot(B0 == mB);
                const unsigned long long blC = __ballot(C0 == mC);
                const unsigned long long blD = __ballot(D0 == mD);
                const int wA = __ffsll(blA) - 1;   // first lane = smallest idx (exact)
                const int wB = __ffsll(blB) - 1;
                const int wC = __ffsll(blC) - 1;
                const int wD = __ffsll(blD) - 1;
                const int xA = __builtin_amdgcn_readlane(IA0, wA);
                const int xB = __builtin_amdgcn_readlane(IB0, wB);
                const int xC = __builtin_amdgcn_readlane(IC0, wC);
                const int xD = __builtin_amdgcn_readlane(ID0, wD);
                if (lane == wA) { A0 = A1; IA0 = IA1; A1 = A2; IA1 = IA2; A2 = A3; IA2 = IA3; A3 = 0u; }
                if (lane == wB) { B0 = B1; IB0 = IB1; B1 = B2; IB1 = IB2; B2 = B3; IB2 = IB3; B3 = 0u; }
                if (lane == wC) { C0 = C1; IC0 = IC1; C1 = C2; IC1 = IC2; C2 = C3; IC2 = IC3; C3 = 0u; }
                if (lane == wD) { D0 = D1; ID0 = ID1; D1 = D2; ID1 = ID2; D2 = D3; ID2 = ID3; D3 = 0u; }
                if (lane == r) {
                    rvA = mA; riA = xA; rvB = mB; riB = xB;
                    rvC = mC; riC = xC; rvD = mD; riD = xD;
                }
            }
            if (lane < KTOP) {
                const int gbase = b * NG + grp * GGRP + gg0;
                const size_t b0 = ((size_t)(gbase + 0) * NCH + chunk) * KTOP + lane;
                const size_t b1 = ((size_t)(gbase + 1) * NCH + chunk) * KTOP + lane;
                const size_t b2 = ((size_t)(gbase + 2) * NCH + chunk) * KTOP + lane;
                const size_t b3 = ((size_t)(gbase + 3) * NCH + chunk) * KTOP + lane;
                candv[b0] = __uint_as_float(rvA);  candi[b0] = riA;
                candv[b1] = __uint_as_float(rvB);  candi[b1] = riB;
                candv[b2] = __uint_as_float(rvC);  candi[b2] = riC;
                candv[b3] = __uint_as_float(rvD);  candi[b3] = riD;
            }
        }
        __syncthreads();
    }

    if (live) {
        const int i = b * NA + a0;
        aux_ws[i] = make_float2(mx, rd);
        inside32[i] = ins;
        bestg[i]    = bg;
    }
}

// ---------------------------------------------------------------------------
// Merge: one wave per (b,g): merge NCH*13=429 candidates -> final top-13.
// (Unchanged — HW-verified, DPP lex-max extraction.)
// ---------------------------------------------------------------------------
__global__ __launch_bounds__(256) void mergeTopK(
    const float* __restrict__ candv,
    const int*   __restrict__ candi,
    int*         __restrict__ topk13)   // (B*G, 13)
{
    const int tid  = threadIdx.x;
    const int lane = tid & 63;
    const int row  = blockIdx.x * 4 + (tid >> 6);   // b*NG + g
    const size_t base = (size_t)row * NCAND;

    float v0 = -FLT_MAX, v1 = -FLT_MAX, v2 = -FLT_MAX, v3 = -FLT_MAX,
          v4 = -FLT_MAX, v5 = -FLT_MAX, v6 = -FLT_MAX;
    int   d0 = 0x7FFFFFFF, d1 = 0x7FFFFFFF, d2 = 0x7FFFFFFF, d3 = 0x7FFFFFFF,
          d4 = 0x7FFFFFFF, d5 = 0x7FFFFFFF, d6 = 0x7FFFFFFF;

    // lane sees <=7 candidates; lex rank-insert (val desc, idx asc), all static
#pragma unroll
    for (int k = 0; k < 7; ++k) {
        const int j0 = lane + 64 * k;
        if (j0 < NCAND) {
            const float x  = candv[base + j0];
            const int   xi = candi[base + j0];
            // rank = count of current entries lex-above (x,xi)
            int r = 0;
            r += (v0 > x) || (v0 == x && d0 < xi);
            r += (v1 > x) || (v1 == x && d1 < xi);
            r += (v2 > x) || (v2 == x && d2 < xi);
            r += (v3 > x) || (v3 == x && d3 < xi);
            r += (v4 > x) || (v4 == x && d4 < xi);
            r += (v5 > x) || (v5 == x && d5 < xi);
            r += (v6 > x) || (v6 == x && d6 < xi);
            // new[j] = j<r ? old[j] : (j==r ? x : old[j-1]); descending order
            v6 = (6 < r) ? v6 : ((6 == r) ? x : v5);  d6 = (6 < r) ? d6 : ((6 == r) ? xi : d5);
            v5 = (5 < r) ? v5 : ((5 == r) ? x : v4);  d5 = (5 < r) ? d5 : ((5 == r) ? xi : d4);
            v4 = (4 < r) ? v4 : ((4 == r) ? x : v3);  d4 = (4 < r) ? d4 : ((4 == r) ? xi : d3);
            v3 = (3 < r) ? v3 : ((3 == r) ? x : v2);  d3 = (3 < r) ? d3 : ((3 == r) ? xi : d2);
            v2 = (2 < r) ? v2 : ((2 == r) ? x : v1);  d2 = (2 < r) ? d2 : ((2 == r) ? xi : d1);
            v1 = (1 < r) ? v1 : ((1 == r) ? x : v0);  d1 = (1 < r) ? d1 : ((1 == r) ? xi : d0);
            v0 = (0 == r) ? x  : v0;                  d0 = (0 == r) ? xi : d0;
        }
    }

    int ri = 0x7FFFFFFF;
#pragma unroll
    for (int rnd = 0; rnd < KTOP; ++rnd) {
        const int hk = __float_as_int(v0);          // head key (signed-monotone)
        const int mk = wave_max_pos(hk);            // wave max value
        // min idx among lanes whose head == mk (idx<=8399 -> key2 >> 0; losers -1)
        const int key2 = (hk == mk) ? (INT_MAX - d0) : -1;
        const int mk2  = wave_max_pos(key2);
        const int midx = INT_MAX - mk2;
        if (hk == mk && d0 == midx) {               // unique winner pops
            v0 = v1; d0 = d1; v1 = v2; d1 = d2; v2 = v3; d2 = d3;
            v3 = v4; d3 = d4; v4 = v5; d4 = d5; v5 = v6; d5 = d6;
            v6 = -FLT_MAX; d6 = 0x7FFFFFFF;
        }
        if (lane == rnd) ri = midx;
    }
    if (lane < KTOP) topk13[(size_t)row * KTOP + lane] = ri;
}

// ---------------------------------------------------------------------------
// Phase C: grid (33, B). Block scatters the batch's 416 winner ids into a
// 256-word LDS bitmask; each anchor thread reads one word. The decoded box
// is recomputed from the dist planes (bit-identical expressions to fusedAB)
// instead of a pb_ws round-trip. out: tb | tc | ts | fg | fg_sum
// ---------------------------------------------------------------------------
__global__ __launch_bounds__(256) void phaseC(
    const float*    __restrict__ gt_bboxes,
    const int*      __restrict__ gt_classes,
    const float*    __restrict__ preds,
    const float*    __restrict__ anchor_points,
    const float2*   __restrict__ aux_ws,
    const int*      __restrict__ topk13,    // (B*G, 13)
    const unsigned* __restrict__ inside32,
    const int*      __restrict__ bestg,
    float*          __restrict__ out)
{
    __shared__ unsigned smask[CHUNK];
    __shared__ float ssum[4];

    const int tid   = threadIdx.x;
    const int b     = blockIdx.y;
    const int abase = blockIdx.x * CHUNK;
    const int a     = abase + tid;

    smask[tid] = 0u;
    __syncthreads();
    for (int j = tid; j < NG * KTOP; j += 256) {
        const int idx = topk13[(size_t)b * NG * KTOP + j];
        const int rel = idx - abase;
        if (rel >= 0 && rel < CHUNK)
            atomicOr(&smask[rel], 1u << (j / KTOP));
    }
    __syncthreads();

    bool fg = false;
    if (a < NA) {
        const int i = b * NA + a;
        unsigned m = smask[tid] & inside32[i];
        const int cnt = __popc(m);

        int tgt;
        if (cnt > 1)       { tgt = bestg[i];     fg = true;  }
        else if (cnt == 1) { tgt = __ffs(m) - 1; fg = true;  }
        else               { tgt = 0;            fg = false; }

        const float f = fg ? 1.0f : 0.0f;
        const float4 gbv = *(const float4*)(gt_bboxes + ((size_t)b * NG + tgt) * 4);
        const float gx1 = gbv.x, gy1 = gbv.y, gx2 = gbv.z, gy2 = gbv.w;
        *(float4*)(out + (size_t)i * 4) = make_float4(gx1 * f, gy1 * f, gx2 * f, gy2 * f);

        const size_t BA = (size_t)NB * NA;
        out[BA * 4 + i] = fg ? (float)gt_classes[b * NG + tgt] : 0.0f;

        float ts = 0.0f;
        if (fg) {
            // recompute box + align(a, tgt) with the same expressions as fusedAB
            const float2 ap = *(const float2*)(anchor_points + (size_t)a * 2);
            const float* db = preds + (size_t)b * (4 + NC) * NA + a;
            const float l  = db[0];
            const float t  = db[(size_t)NA];
            const float r  = db[(size_t)2 * NA];
            const float bo = db[(size_t)3 * NA];
            const float x1 = ap.x - l, y1 = ap.y - t, x2 = ap.x + r, y2 = ap.y + bo;
            const float2 ax = aux_ws[i];
            const float areaA = (x2 - x1) * (y2 - y1);
            const float sag   = (gx2 - gx1) * (gy2 - gy1);
            const float ltx = fmaxf(x1, gx1), lty = fmaxf(y1, gy1);
            const float rbx = fminf(x2, gx2), rby = fminf(y2, gy2);
            const float w = fmaxf(rbx - ltx, 0.0f), h = fmaxf(rby - lty, 0.0f);
            const float inter = w * h;
            const float iou = inter / (areaA + sag - inter + 1e-7f);
            const int cls = gt_classes[b * NG + tgt];
            const float cv = __expf(db[(size_t)(4 + cls) * NA] - ax.x) * ax.y;
            ts = sqrtf(fmaxf(iou, 1e-12f)) * sqrtf(fmaxf(cv, 1e-12f));
        }
        out[BA * 5 + i] = ts;
        out[BA * 6 + i] = f;
    }

    // fg.sum(): ballot per wave -> LDS -> one atomic per block (exact fp32 ints)
    const unsigned long long ball = __ballot(fg);
    if ((tid & 63) == 0) ssum[tid >> 6] = (float)__popcll(ball);
    __syncthreads();
    if (tid == 0) {
        const float s = ssum[0] + ssum[1] + ssum[2] + ssum[3];
        if (s != 0.0f) atomicAdd(&out[(size_t)NB * NA * 7], s);
    }
}

// ---------------------------------------------------------------------------
extern "C" void kernel_launch(void* const* d_in, const int* in_sizes, int n_in,
                              void* d_out, int out_size, void* d_ws, size_t ws_size,
                              hipStream_t stream) {
    const float* preds         = (const float*)d_in[0];
    const float* gt_bboxes     = (const float*)d_in[1];
    const int*   gt_classes    = (const int*)  d_in[2];
    const float* anchor_points = (const float*)d_in[3];
    // d_in[4] stride_tensor: unused by the reference math

    float* out = (float*)d_out;
    const size_t BA = (size_t)NB * NA;

    // workspace carve-up (16B-aligned first): aux | inside | bestg | candv | candi | topk13
    char* ws = (char*)d_ws;
    size_t off = 0;
    float2*   aux_ws   = (float2*)(ws + off);   off += BA * sizeof(float2);
    unsigned* inside32 = (unsigned*)(ws + off); off += BA * sizeof(unsigned);
    int*      bestg    = (int*)(ws + off);      off += BA * sizeof(int);
    float*    candv    = (float*)(ws + off);    off += (size_t)NB * NG * NCAND * sizeof(float);
    int*      candi    = (int*)(ws + off);      off += (size_t)NB * NG * NCAND * sizeof(int);
    int*      topk13   = (int*)(ws + off);

    fusedAB<<<dim3(NCH, NB), 256, 0, stream>>>(preds, gt_bboxes, gt_classes, anchor_points,
                                               aux_ws, inside32, bestg,
                                               candv, candi, out + BA * 7);

    mergeTopK<<<NB * NG / 4, 256, 0, stream>>>(candv, candi, topk13);

    phaseC<<<dim3(NCH, NB), 256, 0, stream>>>(gt_bboxes, gt_classes, preds, anchor_points,
                                              aux_ws, topk13,
                                              inside32, bestg, out);
}